// Round 7
// baseline (5978.027 us; speedup 1.0000x reference)
//
#include <hip/hip_runtime.h>
#include <hip/hip_bf16.h>
#include <stdint.h>

#define S_LEN 256
#define BATCH 128
#define EDIM  256
#define HDIM  512
#define NTAGS 18
#define TCHUNK 16
#define NCHUNK (S_LEN / TCHUNK)

typedef short bf16x8 __attribute__((ext_vector_type(8)));
typedef float f32x4  __attribute__((ext_vector_type(4)));
typedef unsigned short u16;

__device__ __forceinline__ float bf2f(u16 u){
    union { uint32_t i; float f; } v; v.i = ((uint32_t)u) << 16; return v.f;
}
__device__ __forceinline__ u16 f2bf(float f){
    union { float f; uint32_t i; } v; v.f = f;
    uint32_t r = v.i + 0x7FFFu + ((v.i >> 16) & 1u);
    return (u16)(r >> 16);
}
__device__ __forceinline__ float fsig(float x){
    x = fminf(fmaxf(x, -30.f), 30.f);
    return 1.f / (1.f + __expf(-x));
}
__device__ __forceinline__ float ftanh(float x){
    x = fminf(fmaxf(x, -15.f), 15.f);
    float e = __expf(2.f * x);
    return (e - 1.f) / (e + 1.f);
}

// low 32 bits of a generic LDS pointer are the LDS byte offset (HK/CK trick)
#define AS1(p) ((const __attribute__((address_space(1))) void*)(uintptr_t)(const void*)(p))
#define AS3(p) ((__attribute__((address_space(3))) void*)(uint32_t)(uintptr_t)(void*)(p))

// ---------------------------------------------------------------- sentinel
__global__ void ws_sentinel_kernel(float* out, float code){
    out[0] = code;
}

// ---------------------------------------------------------------- cvt / copy
__global__ void cvt_bf16_kernel(const float* __restrict__ src, u16* __restrict__ dst, int n){
    int i = (blockIdx.x * blockDim.x + threadIdx.x) * 4;
    if (i < n){
        float4 v = *(const float4*)(src + i);
        ushort4 o; o.x = f2bf(v.x); o.y = f2bf(v.y); o.z = f2bf(v.z); o.w = f2bf(v.w);
        *(ushort4*)(dst + i) = o;
    }
}
__global__ void copy_f32_kernel(const float* __restrict__ src, float* __restrict__ dst, int n){
    int i = blockIdx.x * blockDim.x + threadIdx.x;
    if (i < n) dst[i] = src[i];
}

// ---------------------------------------------------------------- embedding
// x[s*B + b][e] = (ids[b][s] == 0) ? 0 : emb[id][e], as bf16
__global__ __launch_bounds__(256) void embed_kernel(const int* __restrict__ ids,
                                                    const float* __restrict__ emb,
                                                    u16* __restrict__ x){
    int r = blockIdx.x * 4 + (threadIdx.x >> 6);
    int lane = threadIdx.x & 63;
    int s = r >> 7, b = r & 127;
    int id = ids[b * S_LEN + s];
    float4 v = make_float4(0.f, 0.f, 0.f, 0.f);
    if (id != 0) v = *(const float4*)(emb + (size_t)id * EDIM + lane * 4);
    ushort4 o; o.x = f2bf(v.x); o.y = f2bf(v.y); o.z = f2bf(v.z); o.w = f2bf(v.w);
    *(ushort4*)(x + (size_t)r * EDIM + lane * 4) = o;
}

// ---------------------------------------------------------------- GEMM (NT), generic
// C[M][N] = A[M][K] @ Bw[N][K]^T + bias, bf16 in/out, f32 accum.
// 128x128 tile, BK=32, 4 waves (2x2 of 64x64), global_load_lds staging.
template<int RELU>
__global__ __launch_bounds__(256) void gemm_bt(const u16* __restrict__ A,
                                               const u16* __restrict__ Bw,
                                               const float* __restrict__ bias,
                                               u16* __restrict__ C,
                                               int M, int N, int K){
    __shared__ __align__(16) u16 sA[128 * 32];
    __shared__ __align__(16) u16 sB[128 * 32];
    const int tid  = threadIdx.x;
    const int wid  = tid >> 6;
    const int lane = tid & 63;
    const int l15  = lane & 15, l4 = lane >> 4;
    const int tile_n = blockIdx.x * 128;
    const int tile_m = blockIdx.y * 128;
    const int wr = (wid >> 1) * 64, wc = (wid & 1) * 64;
    f32x4 acc[4][4] = {};

    for (int k0 = 0; k0 < K; k0 += 32){
        if (k0) __syncthreads();
        #pragma unroll
        for (int i = 0; i < 2; ++i){
            int c   = (i * 4 + wid) * 64 + lane;    // 16B-chunk index 0..511
            int row = c >> 2;
            int k8  = (c & 3) * 8;
            __builtin_amdgcn_global_load_lds(AS1(A  + (size_t)(tile_m + row) * K + k0 + k8),
                                             AS3(sA + (size_t)(i * 4 + wid) * 512), 16, 0, 0);
            __builtin_amdgcn_global_load_lds(AS1(Bw + (size_t)(tile_n + row) * K + k0 + k8),
                                             AS3(sB + (size_t)(i * 4 + wid) * 512), 16, 0, 0);
        }
        asm volatile("s_waitcnt vmcnt(0)" ::: "memory");
        __syncthreads();

        bf16x8 af[4], bb[4];
        #pragma unroll
        for (int mi = 0; mi < 4; ++mi)
            af[mi] = *(const bf16x8*)(sA + (wr + mi * 16 + l15) * 32 + l4 * 8);
        #pragma unroll
        for (int ni = 0; ni < 4; ++ni)
            bb[ni] = *(const bf16x8*)(sB + (wc + ni * 16 + l15) * 32 + l4 * 8);
        #pragma unroll
        for (int mi = 0; mi < 4; ++mi)
            #pragma unroll
            for (int ni = 0; ni < 4; ++ni)
                acc[mi][ni] = __builtin_amdgcn_mfma_f32_16x16x32_bf16(af[mi], bb[ni], acc[mi][ni], 0, 0, 0);
    }

    #pragma unroll
    for (int mi = 0; mi < 4; ++mi){
        #pragma unroll
        for (int ni = 0; ni < 4; ++ni){
            #pragma unroll
            for (int j = 0; j < 4; ++j){
                int row = tile_m + wr + mi * 16 + l4 * 4 + j;
                int col = tile_n + wc + ni * 16 + l15;
                float f = acc[mi][ni][j] + bias[col];
                if (RELU) f = fmaxf(f, 0.f);
                C[(size_t)row * N + col] = f2bf(f);
            }
        }
    }
}

// ---------------------------------------------------------------- chunk projection GEMM
// For chunk starting at t0: computes gate pre-activations for TCHUNK steps, both dirs.
//   dir=0 slot k: s = t0+k      xpc[(0*TCHUNK+k)*B + b][n] = A[s*B+b][:] . W[0][n][:] + bias[0][n]
//   dir=1 slot k: s = S-1-t0-k  xpc[(1*TCHUNK+k)*B + b][n] = A[s*B+b][:] . W[1][n][:] + bias[1][n]
// grid = (2048/128, 2*TCHUNK); each block: 128 batch-rows x 128 gate-cols.
__global__ __launch_bounds__(256) void gemm_proj(const u16* __restrict__ A,     // [S*B][K]
                                                 const u16* __restrict__ W,     // [2][2048][K]
                                                 const float* __restrict__ bias,// [2][2048]
                                                 u16* __restrict__ xpc,         // [2*TCHUNK*B][2048]
                                                 int K, int t0){
    __shared__ __align__(16) u16 sA[128 * 32];
    __shared__ __align__(16) u16 sB[128 * 32];
    const int tid  = threadIdx.x;
    const int wid  = tid >> 6;
    const int lane = tid & 63;
    const int l15  = lane & 15, l4 = lane >> 4;
    const int tile_n = blockIdx.x * 128;
    const int slotg  = blockIdx.y;
    const int dir    = slotg / TCHUNK;
    const int slot   = slotg % TCHUNK;
    const int s      = dir ? (S_LEN - 1 - t0 - slot) : (t0 + slot);
    const u16*   Ab = A    + (size_t)s * BATCH * K;
    const u16*   Wb = W    + (size_t)dir * 2048 * K;
    const float* bb_ = bias + dir * 2048;
    u16*         Cb = xpc  + (size_t)slotg * BATCH * 2048;
    const int wr = (wid >> 1) * 64, wc = (wid & 1) * 64;
    f32x4 acc[4][4] = {};

    for (int k0 = 0; k0 < K; k0 += 32){
        if (k0) __syncthreads();
        #pragma unroll
        for (int i = 0; i < 2; ++i){
            int c   = (i * 4 + wid) * 64 + lane;
            int row = c >> 2;
            int k8  = (c & 3) * 8;
            __builtin_amdgcn_global_load_lds(AS1(Ab + (size_t)row * K + k0 + k8),
                                             AS3(sA + (size_t)(i * 4 + wid) * 512), 16, 0, 0);
            __builtin_amdgcn_global_load_lds(AS1(Wb + (size_t)(tile_n + row) * K + k0 + k8),
                                             AS3(sB + (size_t)(i * 4 + wid) * 512), 16, 0, 0);
        }
        asm volatile("s_waitcnt vmcnt(0)" ::: "memory");
        __syncthreads();

        bf16x8 af[4], bfr[4];
        #pragma unroll
        for (int mi = 0; mi < 4; ++mi)
            af[mi] = *(const bf16x8*)(sA + (wr + mi * 16 + l15) * 32 + l4 * 8);
        #pragma unroll
        for (int ni = 0; ni < 4; ++ni)
            bfr[ni] = *(const bf16x8*)(sB + (wc + ni * 16 + l15) * 32 + l4 * 8);
        #pragma unroll
        for (int mi = 0; mi < 4; ++mi)
            #pragma unroll
            for (int ni = 0; ni < 4; ++ni)
                acc[mi][ni] = __builtin_amdgcn_mfma_f32_16x16x32_bf16(af[mi], bfr[ni], acc[mi][ni], 0, 0, 0);
    }

    #pragma unroll
    for (int mi = 0; mi < 4; ++mi){
        #pragma unroll
        for (int ni = 0; ni < 4; ++ni){
            #pragma unroll
            for (int j = 0; j < 4; ++j){
                int row = wr + mi * 16 + l4 * 4 + j;      // batch index b
                int col = tile_n + wc + ni * 16 + l15;    // gate col 0..2047
                Cb[(size_t)row * 2048 + col] = f2bf(acc[mi][ni][j] + bb_[col]);
            }
        }
    }
}

// ---------------------------------------------------------------- LSTM step
// One launch per timestep t (global); both directions. 512 blocks x 1 wave.
// Reads gate pre-activations from the chunk buffer at slot k = t - t0.
__global__ __launch_bounds__(64) void lstm_step_kernel(const u16* __restrict__ xpc,     // [2*TCHUNK*B][2048]
                                                       const u16* __restrict__ Whh,     // [2][2048][512]
                                                       const u16* __restrict__ h_in,    // [2][128][512]
                                                       u16* __restrict__ h_out,
                                                       const float* __restrict__ c_in,  // [2][128][512]
                                                       float* __restrict__ c_out,
                                                       u16* __restrict__ hs,            // [S*B][1024]
                                                       int t, int k){
    int w   = blockIdx.x;
    int dir = w >> 8;
    int rem = w & 255;
    int rb  = (rem >> 5) * 16;   // batch-row base
    int hb  = (rem & 31) * 16;   // h-unit base
    int lane = threadIdx.x;
    int l15 = lane & 15, l4 = lane >> 4;
    f32x4 acc[4] = {};

    if (t > 0){
        const u16* hp = h_in + dir * BATCH * HDIM;
        const u16* Wd = Whh + (size_t)dir * 4 * HDIM * HDIM;
        #pragma unroll 4
        for (int kk = 0; kk < HDIM; kk += 32){
            bf16x8 a = *(const bf16x8*)(hp + (size_t)(rb + l15) * HDIM + kk + l4 * 8);
            #pragma unroll
            for (int g = 0; g < 4; ++g){
                bf16x8 b = *(const bf16x8*)(Wd + (size_t)(g * HDIM + hb + l15) * HDIM + kk + l4 * 8);
                acc[g] = __builtin_amdgcn_mfma_f32_16x16x32_bf16(a, b, acc[g], 0, 0, 0);
            }
        }
    }

    int s = dir ? (S_LEN - 1 - t) : t;
    #pragma unroll
    for (int j = 0; j < 4; ++j){
        int brow = rb + l4 * 4 + j;
        int hu   = hb + l15;
        size_t xr = ((size_t)(dir * TCHUNK + k) * BATCH + brow) * 2048;
        float gi = acc[0][j] + bf2f(xpc[xr + hu]);
        float gf = acc[1][j] + bf2f(xpc[xr + 512 + hu]);
        float gg = acc[2][j] + bf2f(xpc[xr + 1024 + hu]);
        float go = acc[3][j] + bf2f(xpc[xr + 1536 + hu]);
        float c  = (t > 0) ? c_in[(dir * BATCH + brow) * HDIM + hu] : 0.f;
        float cn = fsig(gf) * c + fsig(gi) * ftanh(gg);
        float hn = fsig(go) * ftanh(cn);
        c_out[(dir * BATCH + brow) * HDIM + hu] = cn;
        h_out[(dir * BATCH + brow) * HDIM + hu] = f2bf(hn);
        hs[((size_t)s * BATCH + brow) * (2 * HDIM) + dir * HDIM + hu] = f2bf(hn);
    }
}

// ---------------------------------------------------------------- emissions
__global__ __launch_bounds__(256) void emissions_kernel(const u16* __restrict__ h,
                                                        const u16* __restrict__ clsw,
                                                        const float* __restrict__ clsb,
                                                        float* __restrict__ em){
    int r = blockIdx.x * 4 + (threadIdx.x >> 6);
    int lane = threadIdx.x & 63;
    bf16x8 hv = *(const bf16x8*)(h + (size_t)r * HDIM + lane * 8);
    float hf[8];
    #pragma unroll
    for (int k = 0; k < 8; ++k) hf[k] = bf2f((u16)hv[k]);
    #pragma unroll
    for (int tg = 0; tg < NTAGS; ++tg){
        bf16x8 wv = *(const bf16x8*)(clsw + tg * HDIM + lane * 8);
        float p = 0.f;
        #pragma unroll
        for (int k = 0; k < 8; ++k) p += hf[k] * bf2f((u16)wv[k]);
        #pragma unroll
        for (int off = 32; off; off >>= 1) p += __shfl_xor(p, off);
        if (lane == 0) em[(size_t)r * NTAGS + tg] = p + clsb[tg];
    }
}

// ---------------------------------------------------------------- CRF
__global__ __launch_bounds__(64) void crf_kernel(const int* __restrict__ ids,
                                                 const int* __restrict__ tags,
                                                 const float* __restrict__ em,
                                                 const float* __restrict__ trans,
                                                 const float* __restrict__ startt,
                                                 const float* __restrict__ endt,
                                                 float* __restrict__ llh){
    __shared__ float sT[NTAGS * NTAGS];
    __shared__ float sAl[2][32];
    int b = blockIdx.x;
    int lane = threadIdx.x;
    for (int i = lane; i < NTAGS * NTAGS; i += 64) sT[i] = trans[i];
    __syncthreads();

    // numerator (gold path), lane-parallel over time
    float part = 0.f; int mc = 0;
    for (int s = lane; s < S_LEN; s += 64){
        int id = ids[b * S_LEN + s];
        int m = (id != 0);
        mc += m;
        if (s >= 1 && m){
            int tp = tags[b * S_LEN + s - 1];
            int tc = tags[b * S_LEN + s];
            part += sT[tp * NTAGS + tc] + em[((size_t)s * BATCH + b) * NTAGS + tc];
        }
    }
    #pragma unroll
    for (int off = 32; off; off >>= 1){
        part += __shfl_xor(part, off);
        mc   += __shfl_xor(mc, off);
    }
    int t0 = tags[b * S_LEN];
    float num = startt[t0] + em[(size_t)b * NTAGS + t0] + part;
    int se = mc - 1;
    num += endt[tags[b * S_LEN + se]];

    // denominator: forward algorithm, lanes 0..17
    int j = lane;
    float alpha = -1e30f;
    if (j < NTAGS){
        alpha = startt[j] + em[(size_t)b * NTAGS + j];
        sAl[0][j] = alpha;
    }
    int cur = 0;
    for (int s = 1; s < S_LEN; ++s){
        int m = (ids[b * S_LEN + s] != 0);
        if (j < NTAGS){
            float e = em[((size_t)s * BATCH + b) * NTAGS + j];
            float mx = -1e30f;
            #pragma unroll
            for (int i = 0; i < NTAGS; ++i) mx = fmaxf(mx, sAl[cur][i] + sT[i * NTAGS + j]);
            float sum = 0.f;
            #pragma unroll
            for (int i = 0; i < NTAGS; ++i) sum += __expf(sAl[cur][i] + sT[i * NTAGS + j] - mx);
            float ns = mx + __logf(sum) + e;
            float na = m ? ns : alpha;
            alpha = na;
            sAl[cur ^ 1][j] = na;
        }
        cur ^= 1;
    }
    if (j < NTAGS) sAl[cur][j] = alpha + endt[j];
    float mx = -1e30f;
    #pragma unroll
    for (int i = 0; i < NTAGS; ++i) mx = fmaxf(mx, sAl[cur][i]);
    float sum = 0.f;
    #pragma unroll
    for (int i = 0; i < NTAGS; ++i) sum += __expf(sAl[cur][i] - mx);
    float den = mx + __logf(sum);
    if (lane == 0) llh[b] = num - den;
}

__global__ void final_reduce_kernel(const float* __restrict__ llh, float* __restrict__ out){
    int l = threadIdx.x;
    float v = llh[l] + llh[l + 64];
    #pragma unroll
    for (int off = 32; off; off >>= 1) v += __shfl_xor(v, off);
    if (l == 0) out[0] = v * (1.f / 128.f);
}

// ---------------------------------------------------------------- host
extern "C" void kernel_launch(void* const* d_in, const int* in_sizes, int n_in,
                              void* d_out, int out_size, void* d_ws, size_t ws_size,
                              hipStream_t stream){
    const int*   ids      = (const int*)d_in[0];
    const int*   tags     = (const int*)d_in[1];
    const float* emb      = (const float*)d_in[2];
    const float* w_ih_l0f = (const float*)d_in[3];
    const float* w_hh_l0f = (const float*)d_in[4];
    const float* b_l0f    = (const float*)d_in[5];
    const float* w_ih_l0b = (const float*)d_in[6];
    const float* w_hh_l0b = (const float*)d_in[7];
    const float* b_l0b    = (const float*)d_in[8];
    const float* w_ih_l1f = (const float*)d_in[9];
    const float* w_hh_l1f = (const float*)d_in[10];
    const float* b_l1f    = (const float*)d_in[11];
    const float* w_ih_l1b = (const float*)d_in[12];
    const float* w_hh_l1b = (const float*)d_in[13];
    const float* b_l1b    = (const float*)d_in[14];
    const float* fc_w     = (const float*)d_in[15];
    const float* fc_b     = (const float*)d_in[16];
    const float* cls_w    = (const float*)d_in[17];
    const float* cls_b    = (const float*)d_in[18];
    const float* trans    = (const float*)d_in[19];
    const float* startt   = (const float*)d_in[20];
    const float* endt     = (const float*)d_in[21];
    (void)in_sizes; (void)n_in; (void)out_size;

    const size_t M = (size_t)S_LEN * BATCH;   // 32768
    char* ws = (char*)d_ws;
    size_t off = 0;
    auto take = [&](size_t bytes) -> char* {
        char* p = ws + off;
        off += (bytes + 255) & ~(size_t)255;
        return p;
    };
    // weights (bf16) + biases
    u16*   W0   = (u16*)  take((size_t)4096 * 256 * 2);            // [2][2048][256]
    u16*   Whh0 = (u16*)  take((size_t)2 * 2048 * 512 * 2);
    u16*   W1   = (u16*)  take((size_t)4096 * 1024 * 2);           // [2][2048][1024]
    u16*   Whh1 = (u16*)  take((size_t)2 * 2048 * 512 * 2);
    u16*   fcwb = (u16*)  take((size_t)512 * 1024 * 2);
    u16*   cls16= (u16*)  take((size_t)NTAGS * 512 * 2);
    float* b0   = (float*)take(4096 * 4);
    float* b1   = (float*)take(4096 * 4);
    // activations — xbf and xpc adjacent so hfc (32 MB) can alias both
    u16*   xbf  = (u16*)  take(M * EDIM * 2);                      // 16 MB
    u16*   xpc  = (u16*)  take((size_t)2 * TCHUNK * BATCH * 2048 * 2); // 16 MB
    u16*   hfc  = xbf;                                             // alias (FC out, 32 MB)
    u16*   hs0  = (u16*)  take(M * 1024 * 2);                      // 64 MB
    u16*   hs1  = (u16*)  take(M * 1024 * 2);                      // 64 MB
    u16*   hbuf = (u16*)  take((size_t)2 * 2 * BATCH * HDIM * 2);  // ping-pong h
    float* cbuf = (float*)take((size_t)2 * 2 * BATCH * HDIM * 4);  // ping-pong c
    float* em   = (float*)take(M * NTAGS * 4);
    float* llh  = (float*)take(BATCH * 4);

    if (off > ws_size){
        // Workspace too small: report a decodable sentinel instead of faulting.
        ws_sentinel_kernel<<<1, 1, 0, stream>>>((float*)d_out,
                                                -1.0e6f - (float)(ws_size >> 20));
        return;
    }

    auto cvt = [&](const float* s, u16* d, int n){
        cvt_bf16_kernel<<<(n / 4 + 255) / 256, 256, 0, stream>>>(s, d, n);
    };
    auto cpy = [&](const float* s, float* d, int n){
        copy_f32_kernel<<<(n + 255) / 256, 256, 0, stream>>>(s, d, n);
    };

    cvt(w_ih_l0f, W0, 2048 * 256);
    cvt(w_ih_l0b, W0 + (size_t)2048 * 256, 2048 * 256);
    cvt(w_hh_l0f, Whh0, 2048 * 512);
    cvt(w_hh_l0b, Whh0 + (size_t)2048 * 512, 2048 * 512);
    cvt(w_ih_l1f, W1, 2048 * 1024);
    cvt(w_ih_l1b, W1 + (size_t)2048 * 1024, 2048 * 1024);
    cvt(w_hh_l1f, Whh1, 2048 * 512);
    cvt(w_hh_l1b, Whh1 + (size_t)2048 * 512, 2048 * 512);
    cvt(fc_w, fcwb, 512 * 1024);
    cvt(cls_w, cls16, NTAGS * 512);
    cpy(b_l0f, b0, 2048); cpy(b_l0b, b0 + 2048, 2048);
    cpy(b_l1f, b1, 2048); cpy(b_l1b, b1 + 2048, 2048);

    embed_kernel<<<8192, 256, 0, stream>>>(ids, emb, xbf);

    // ---- layer 0: chunked projection + recurrent steps ----
    for (int c = 0; c < NCHUNK; ++c){
        gemm_proj<<<dim3(16, 2 * TCHUNK), 256, 0, stream>>>(xbf, W0, b0, xpc, EDIM, c * TCHUNK);
        for (int k = 0; k < TCHUNK; ++k){
            int t = c * TCHUNK + k;
            const u16*   hi = hbuf + ((t + 1) & 1) * (2 * BATCH * HDIM);
            u16*         ho = hbuf + (t & 1) * (2 * BATCH * HDIM);
            const float* ci = cbuf + ((t + 1) & 1) * (2 * BATCH * HDIM);
            float*       co = cbuf + (t & 1) * (2 * BATCH * HDIM);
            lstm_step_kernel<<<512, 64, 0, stream>>>(xpc, Whh0, hi, ho, ci, co, hs0, t, k);
        }
    }
    // ---- layer 1 ----
    for (int c = 0; c < NCHUNK; ++c){
        gemm_proj<<<dim3(16, 2 * TCHUNK), 256, 0, stream>>>(hs0, W1, b1, xpc, 2 * HDIM, c * TCHUNK);
        for (int k = 0; k < TCHUNK; ++k){
            int t = c * TCHUNK + k;
            const u16*   hi = hbuf + ((t + 1) & 1) * (2 * BATCH * HDIM);
            u16*         ho = hbuf + (t & 1) * (2 * BATCH * HDIM);
            const float* ci = cbuf + ((t + 1) & 1) * (2 * BATCH * HDIM);
            float*       co = cbuf + (t & 1) * (2 * BATCH * HDIM);
            lstm_step_kernel<<<512, 64, 0, stream>>>(xpc, Whh1, hi, ho, ci, co, hs1, t, k);
        }
    }
    // ---- FC + ReLU (writes hfc, aliasing dead xbf+xpc) ----
    {
        dim3 g(512 / 128, 32768 / 128);
        gemm_bt<1><<<g, 256, 0, stream>>>(hs1, fcwb, fc_b, hfc, 32768, 512, 1024);
    }
    emissions_kernel<<<8192, 256, 0, stream>>>(hfc, cls16, cls_b, em);
    crf_kernel<<<BATCH, 64, 0, stream>>>(ids, tags, em, trans, startt, endt, llh);
    final_reduce_kernel<<<1, 64, 0, stream>>>(llh, (float*)d_out);
}